// Round 27
// baseline (487.995 us; speedup 1.0000x reference)
//
#include <hip/hip_runtime.h>
#include <cmath>

#define B_ 2
#define S_ 512
#define D_ 1024
#define H_ 16
#define HD 64
#define M_ 8192
#define HDIM 1024
#define SCALE 0.125f
#define LCAP 12    // per-lane private candidates; 16 lanes/query -> top-192 screen
#define NRES 3     // rescored candidates per lane (top-48 of 192 by key)

using bf16x8 = __attribute__((ext_vector_type(8))) short;
using f32x4  = __attribute__((ext_vector_type(4))) float;

// pack two f32 (hi,lo) -> one u32 holding [bf16(lo) | bf16(hi)<<16] (truncation)
__device__ inline unsigned pkbf(unsigned hi, unsigned lo) {
    return __builtin_amdgcn_perm(hi, lo, 0x07060302u);
}
// monotone u16 sort keys for 2 packed bf16 (order-preserving for floats)
__device__ inline unsigned key2(unsigned u) {
    unsigned m = u & 0x80008000u;
    return u ^ (m - (m >> 15)) ^ 0x80008000u;
}

// DPP lane moves (full-rate VALU). 0x140=row_mirror (i^15 within 16),
// 0x141=row_half_mirror (i^7), 0x4E=quad_perm xor2, 0xB1=quad_perm xor1.
template<int CTRL>
__device__ inline int dppmov(int x) {
    return __builtin_amdgcn_update_dpp(0, x, CTRL, 0xF, 0xF, true);
}

// ---------------- K0+K1 fused: tobf16 (blocks 0..8191) + QKV GEMM ----------
// tobf16 is HBM-bound (96 MB, VALU idle); qkv is VALU-bound (HBM idle).
// Independent inputs/outputs -> fuse into one launch so they overlap:
// combined ~= max(qkv, tobf16) instead of sum, plus one launch gap saved.
__global__ __launch_bounds__(256) void qkv_tobf16(
    const float* __restrict__ memk, unsigned short* __restrict__ kb16,
    const float* __restrict__ A,
    const float* __restrict__ Wq, const float* __restrict__ bq,
    const float* __restrict__ Wk, const float* __restrict__ bk,
    const float* __restrict__ Wv, const float* __restrict__ bv,
    float* __restrict__ qo, float* __restrict__ ko, float* __restrict__ vo)
{
    if (blockIdx.x < 8192) {
        // ---- tobf16 path (identical arithmetic to the standalone kernel) --
        size_t i = ((size_t)blockIdx.x*256 + threadIdx.x) * 8;
        f32x4 a = *(const f32x4*)&memk[i];
        f32x4 b = *(const f32x4*)&memk[i+4];
        union { bf16x8 v; unsigned u[4]; } u;
        u.u[0] = pkbf(__float_as_uint(a.y), __float_as_uint(a.x));
        u.u[1] = pkbf(__float_as_uint(a.w), __float_as_uint(a.z));
        u.u[2] = pkbf(__float_as_uint(b.y), __float_as_uint(b.x));
        u.u[3] = pkbf(__float_as_uint(b.w), __float_as_uint(b.z));
        *(bf16x8*)&kb16[i] = u.v;
        return;
    }
    // ---- qkv path (identical arithmetic to the standalone kernel) ---------
    const int id2 = blockIdx.x - 8192;          // 0..767
    const int which = id2 >> 8;                 // 0..2
    const int rem = id2 & 255;
    const int rb = (rem >> 4) * 64, cb = (rem & 15) * 64;
    const float* W    = (which==0)?Wq:((which==1)?Wk:Wv);
    const float* bias = (which==0)?bq:((which==1)?bk:bv);
    float* out        = (which==0)?qo:((which==1)?ko:vo);
    __shared__ float As[16][68];
    __shared__ float Bs[16][68];
    const int tid = threadIdx.x;
    const int ty = tid>>4, tx = tid&15;
    const int ar = tid>>2, ac4 = (tid&3)<<2;
    const int bkr = tid>>4, bc4 = (tid&15)<<2;
    float acc[4][4] = {};
    for (int kb=0; kb<D_; kb+=16) {
        float4 av  = *(const float4*)&A[(size_t)(rb+ar)*D_ + kb + ac4];
        float4 bvv = *(const float4*)&W[(size_t)(kb+bkr)*HDIM + cb + bc4];
        __syncthreads();
        As[ac4+0][ar]=av.x; As[ac4+1][ar]=av.y; As[ac4+2][ar]=av.z; As[ac4+3][ar]=av.w;
        *(float4*)&Bs[bkr][bc4] = bvv;
        __syncthreads();
        #pragma unroll
        for (int kk=0; kk<16; kk++) {
            float a[4], b[4];
            *(float4*)a = *(const float4*)&As[kk][ty<<2];
            *(float4*)b = *(const float4*)&Bs[kk][tx<<2];
            #pragma unroll
            for (int i=0;i<4;i++)
                #pragma unroll
                for (int j=0;j<4;j++) acc[i][j] += a[i]*b[j];
        }
    }
    const int c0 = cb + (tx<<2);
    float4 bb = *(const float4*)&bias[c0];
    const int h = c0>>6, dd = c0&63;
    #pragma unroll
    for (int i=0;i<4;i++) {
        int n = rb + (ty<<2) + i;
        int b = n>>9, s = n&511;
        float4 r;
        r.x = acc[i][0]+bb.x; r.y = acc[i][1]+bb.y;
        r.z = acc[i][2]+bb.z; r.w = acc[i][3]+bb.w;
        *(float4*)&out[((size_t)(b*H_+h)*S_ + s)*HD + dd] = r;
    }
}

// ---------------- K6: output projection GEMM ----------------
__global__ __launch_bounds__(256) void out_gemm(
    const float* __restrict__ A, const float* __restrict__ W, float* __restrict__ out)
{
    const int rb = blockIdx.y*64, cb = blockIdx.x*64;
    __shared__ float As[16][68];
    __shared__ float Bs[16][68];
    const int tid = threadIdx.x;
    const int ty = tid>>4, tx = tid&15;
    const int ar = tid>>2, ac4 = (tid&3)<<2;
    const int bkr = tid>>4, bc4 = (tid&15)<<2;
    float acc[4][4] = {};
    for (int kb=0; kb<HDIM; kb+=16) {
        float4 av  = *(const float4*)&A[(size_t)(rb+ar)*HDIM + kb + ac4];
        float4 bvv = *(const float4*)&W[(size_t)(kb+bkr)*D_ + cb + bc4];
        __syncthreads();
        As[ac4+0][ar]=av.x; As[ac4+1][ar]=av.y; As[ac4+2][ar]=av.z; As[ac4+3][ar]=av.w;
        *(float4*)&Bs[bkr][bc4] = bvv;
        __syncthreads();
        #pragma unroll
        for (int kk=0; kk<16; kk++) {
            float a[4], b[4];
            *(float4*)a = *(const float4*)&As[kk][ty<<2];
            *(float4*)b = *(const float4*)&Bs[kk][tx<<2];
            #pragma unroll
            for (int i=0;i<4;i++)
                #pragma unroll
                for (int j=0;j<4;j++) acc[i][j] += a[i]*b[j];
        }
    }
    const int c0 = cb + (tx<<2);
    #pragma unroll
    for (int i=0;i<4;i++) {
        int n = rb + (ty<<2) + i;
        float4 r;
        r.x=acc[i][0]; r.y=acc[i][1]; r.z=acc[i][2]; r.w=acc[i][3];
        *(float4*)&out[(size_t)n*D_ + c0] = r;
    }
}

// ---------------- K2: RoPE in-place on q,k ----------------
__global__ __launch_bounds__(256) void rope_kernel(
    float* __restrict__ q, float* __restrict__ k,
    const float* __restrict__ cosb, const float* __restrict__ sinb)
{
    int t = blockIdx.x*256 + threadIdx.x;
    int pair = t & 31;
    int s    = (t>>5) & 511;
    int bh   = (t>>14) & 31;
    float* x = (t>>19) ? k : q;
    float* xb = x + ((size_t)(bh*S_ + s))*HD;
    float c  = cosb[s*HD + pair];
    float sn = sinb[s*HD + pair];
    float x1 = xb[pair], x2 = xb[pair+32];
    xb[pair]    = x1*c - x2*sn;
    xb[pair+32] = x2*c + x1*sn;
}

// ---------------- K3: MFMA sim + screen (dbuf, wave-skip ladder) -----------
// 256 blocks x 1024 thr (16 waves). Block: 64 queries x full M, tile=128,
// bf16 stream, double-buffered Ks+sc, ONE barrier/tile. Ladder guarded by
// __any(key > lane-min): skipping is exact (below-min inserts are no-ops on
// a sorted-desc list). Screen/rescore semantics identical to R21/R22.
__global__ __launch_bounds__(1024, 4) void sim_topk_mfma(
    const float* __restrict__ q, const float* __restrict__ memk,
    const unsigned short* __restrict__ kb16,
    float* __restrict__ topV, int* __restrict__ topI)
{
    __shared__ unsigned short sc[2][64][136];
    __shared__ __align__(16) float qs[64][64];
    __shared__ __align__(16) unsigned short Ks[2][128][76];
    const int tid = threadIdx.x;
    int id = blockIdx.x;                 // 0..255
    int virt = (id & 7)*32 + (id >> 3);
    const int bh = virt >> 3, qt = virt & 7;
    const float* qbase = q + ((size_t)bh*S_ + qt*64)*HD;
    const float* kbase = memk + (size_t)bh*M_*HD;
    const unsigned short* k16 = kb16 + (size_t)bh*M_*HD;

    {   // stage q f32 (64x64): one f32x4 per thread
        int r = tid >> 4, c = (tid & 15) << 2;
        *(f32x4*)&qs[r][c] = *(const f32x4*)&qbase[(size_t)r*HD + c];
    }
    __syncthreads();

    const int lane = tid & 63;
    const int w  = tid >> 6;                  // wave 0..15
    const int s8 = w & 7;                     // m-subtile (rows s8*16..+15)
    const int qg = w >> 3;                    // qh-group: qh = 2*qg, 2*qg+1
    const int fr = lane & 15, fc = lane >> 4; // frag row / k-chunk

    bf16x8 bq[2][2];
    #pragma unroll
    for (int j = 0; j < 2; j++)
        #pragma unroll
        for (int kc = 0; kc < 2; kc++) {
            const float* p = &qs[(2*qg + j)*16 + fr][kc*32 + 8*fc];
            union { bf16x8 v; unsigned u[4]; } u;
            #pragma unroll
            for (int jj = 0; jj < 4; jj++)
                u.u[jj] = pkbf(__float_as_uint(p[2*jj+1]), __float_as_uint(p[2*jj]));
            bq[j][kc] = u.v;
        }

    const int ql = tid >> 4, lg = tid & 15;   // query row / lane-in-group
    unsigned xs[LCAP];
    #pragma unroll
    for (int s = 0; s < LCAP; s++) xs[s] = 0u;

    const int srow = tid >> 3, scol = (tid & 7) << 3;

    uint4 pfu;
    {
        uint4 t0 = *(const uint4*)&k16[(size_t)srow*HD + scol];
        *(uint4*)&Ks[0][srow][scol] = t0;
        pfu = *(const uint4*)&k16[(size_t)(128 + srow)*HD + scol];
    }
    __syncthreads();   // Ks[0] ready

    for (int it = 0; it < 64; it++) {
        const int cur = it & 1, nxt = cur ^ 1;
        if (it < 63) {
            *(uint4*)&Ks[nxt][srow][scol] = pfu;
        }
        if (it < 62) {
            pfu = *(const uint4*)&k16[(size_t)((it+2)*128 + srow)*HD + scol];
        }
        {
            bf16x8 a0 = *(const bf16x8*)&Ks[cur][s8*16 + fr][8*fc];
            bf16x8 a1 = *(const bf16x8*)&Ks[cur][s8*16 + fr][32 + 8*fc];
            #pragma unroll
            for (int j = 0; j < 2; j++) {
                f32x4 acc = (f32x4){0.f, 0.f, 0.f, 0.f};
                acc = __builtin_amdgcn_mfma_f32_16x16x32_bf16(a0, bq[j][0], acc, 0,0,0);
                acc = __builtin_amdgcn_mfma_f32_16x16x32_bf16(a1, bq[j][1], acc, 0,0,0);
                unsigned k0 = key2(pkbf(__float_as_uint(acc.y), __float_as_uint(acc.x)));
                unsigned k1 = key2(pkbf(__float_as_uint(acc.w), __float_as_uint(acc.z)));
                uint2 kk; kk.x = k0; kk.y = k1;
                *(uint2*)&sc[cur][(2*qg + j)*16 + fr][s8*16 + 4*fc] = kk;
            }
        }
        if (it > 0) {
            uint4 w0v = *(const uint4*)&sc[cur^1][ql][lg << 3];
            unsigned wbuf[4] = {w0v.x, w0v.y, w0v.z, w0v.w};
            const unsigned ibase = (unsigned)((it-1)*128 + (lg << 3));
            #pragma unroll
            for (int p = 0; p < 4; p++) {
                unsigned wk = wbuf[p];
                unsigned ve = (wk << 16) | (ibase + 2*p);
                unsigned vo = (wk & 0xFFFF0000u) | (ibase + 2*p + 1);
                if (__any(ve > xs[LCAP-1] || vo > xs[LCAP-1])) {
                    #pragma unroll
                    for (int s = 0; s < LCAP; s++) {
                        unsigned mx = xs[s] > ve ? xs[s] : ve;
                        unsigned mn = xs[s] > ve ? ve : xs[s];
                        xs[s] = mx; ve = mn;
                    }
                    #pragma unroll
                    for (int s = 0; s < LCAP; s++) {
                        unsigned mx = xs[s] > vo ? xs[s] : vo;
                        unsigned mn = xs[s] > vo ? vo : xs[s];
                        xs[s] = mx; vo = mn;
                    }
                }
            }
        }
        __syncthreads();
    }
    {
        uint4 w0v = *(const uint4*)&sc[1][ql][lg << 3];
        unsigned wbuf[4] = {w0v.x, w0v.y, w0v.z, w0v.w};
        const unsigned ibase = (unsigned)(63*128 + (lg << 3));
        #pragma unroll
        for (int p = 0; p < 4; p++) {
            unsigned wk = wbuf[p];
            unsigned ve = (wk << 16) | (ibase + 2*p);
            unsigned vo = (wk & 0xFFFF0000u) | (ibase + 2*p + 1);
            if (__any(ve > xs[LCAP-1] || vo > xs[LCAP-1])) {
                #pragma unroll
                for (int s = 0; s < LCAP; s++) {
                    unsigned mx = xs[s] > ve ? xs[s] : ve;
                    unsigned mn = xs[s] > ve ? ve : xs[s];
                    xs[s] = mx; ve = mn;
                }
                #pragma unroll
                for (int s = 0; s < LCAP; s++) {
                    unsigned mx = xs[s] > vo ? xs[s] : vo;
                    unsigned mn = xs[s] > vo ? vo : xs[s];
                    xs[s] = mx; vo = mn;
                }
            }
        }
    }

    // ---- register extract: group top-48 by key -> 3 collector slots/lane --
    unsigned rc[NRES];
    #pragma unroll
    for (int it = 0; it < 48; it++) {
        unsigned gm = xs[0]; int go = lg;
        { unsigned ov=(unsigned)dppmov<0x140>((int)gm); int oo=dppmov<0x140>(go);
          if (ov > gm) { gm = ov; go = oo; } }
        { unsigned ov=(unsigned)dppmov<0x141>((int)gm); int oo=dppmov<0x141>(go);
          if (ov > gm) { gm = ov; go = oo; } }
        { unsigned ov=(unsigned)dppmov<0x4E>((int)gm);  int oo=dppmov<0x4E>(go);
          if (ov > gm) { gm = ov; go = oo; } }
        { unsigned ov=(unsigned)dppmov<0xB1>((int)gm);  int oo=dppmov<0xB1>(go);
          if (ov > gm) { gm = ov; go = oo; } }
        if (go == lg) {
            #pragma unroll
            for (int s = 0; s < LCAP-1; s++) xs[s] = xs[s+1];
            xs[LCAP-1] = 0u;
        }
        if ((it & 15) == lg) rc[it >> 4] = gm;
    }

    // ---- exact f32 rescore of my NRES candidates ----
    float rsv[NRES]; int rsi[NRES];
    #pragma unroll
    for (int s2 = 0; s2 < NRES; s2++) {
        int idx = (int)(rc[s2] & 0xFFFFu);
        const float* kr = &kbase[(size_t)idx * HD];
        float accr = 0.f;
        #pragma unroll
        for (int j = 0; j < 64; j += 4) {
            f32x4 kv = *(const f32x4*)&kr[j];
            f32x4 qv = *(const f32x4*)&qs[ql][j];
            accr += qv.x*kv.x + qv.y*kv.y + qv.z*kv.z + qv.w*kv.w;
        }
        rsv[s2] = accr; rsi[s2] = idx;
    }
    // ---- exact top-32 of 48 by extract-max (16-lane DPP argmax) ----
    const int qgb = bh*S_ + qt*64;
    float* tVo = &topV[(size_t)(qgb + ql)*32];
    int*   tIo = &topI[(size_t)(qgb + ql)*32];
    #pragma unroll 1
    for (int it = 0; it < 32; it++) {
        float mv = rsv[0]; int ms = 0;
        if (rsv[1] > mv) { mv = rsv[1]; ms = 1; }
        if (rsv[2] > mv) { mv = rsv[2]; ms = 2; }
        int owner = (lg << 2) | ms;
        { float ovf=__int_as_float(dppmov<0x140>(__float_as_int(mv))); int oo=dppmov<0x140>(owner);
          if (ovf>mv || (ovf==mv && oo<owner)) { mv=ovf; owner=oo; } }
        { float ovf=__int_as_float(dppmov<0x141>(__float_as_int(mv))); int oo=dppmov<0x141>(owner);
          if (ovf>mv || (ovf==mv && oo<owner)) { mv=ovf; owner=oo; } }
        { float ovf=__int_as_float(dppmov<0x4E>(__float_as_int(mv)));  int oo=dppmov<0x4E>(owner);
          if (ovf>mv || (ovf==mv && oo<owner)) { mv=ovf; owner=oo; } }
        { float ovf=__int_as_float(dppmov<0xB1>(__float_as_int(mv)));  int oo=dppmov<0xB1>(owner);
          if (ovf>mv || (ovf==mv && oo<owner)) { mv=ovf; owner=oo; } }
        if ((owner >> 2) == lg) {
            int ms2 = owner & 3;
            int idx = rsi[0];
            if (ms2 == 1) idx = rsi[1];
            else if (ms2 == 2) idx = rsi[2];
            if (ms2 == 0) rsv[0] = -INFINITY;
            else if (ms2 == 1) rsv[1] = -INFINITY;
            else rsv[2] = -INFINITY;
            tVo[it] = mv; tIo[it] = idx;
        }
    }
}

// ---------------- K5: fused local-causal + memory attention ----------------
__global__ __launch_bounds__(256) void attn_fused(
    const float* __restrict__ q, const float* __restrict__ k, const float* __restrict__ v,
    const float* __restrict__ topV, const int* __restrict__ topI,
    const float* __restrict__ memv, float* __restrict__ attn)
{
    __shared__ float Ks[64][68];
    __shared__ float Vs[64][68];
    __shared__ float Qs[32][68];
    __shared__ float pt[32][68];
    const int tid = threadIdx.x;
    const int qt = blockIdx.x, bh = blockIdx.y;
    const float* qbase = q + ((size_t)bh*S_ + qt*32)*HD;
    {
        int fi = tid; int r = fi>>4, c = (fi&15)<<2;
        float4 t4 = *(const float4*)&qbase[(size_t)r*HD + c];
        t4.x*=SCALE; t4.y*=SCALE; t4.z*=SCALE; t4.w*=SCALE;
        *(float4*)&Qs[r][c] = t4;
        fi = tid+256; r = fi>>4; c = (fi&15)<<2;
        t4 = *(const float4*)&qbase[(size_t)r*HD + c];
        t4.x*=SCALE; t4.y*=SCALE; t4.z*=SCALE; t4.w*=SCALE;
        *(float4*)&Qs[r][c] = t4;
    }
    __syncthreads();
    const int ql = tid>>3, lg = tid&7;
    const int dd0 = lg<<3;
    float qreg[64];
    #pragma unroll
    for (int j=0;j<64;j+=4) *(float4*)&qreg[j] = *(const float4*)&Qs[ql][j];
    const int qpos = qt*32 + ql;
    const size_t qg = (size_t)bh*S_ + qpos;

    float m = -INFINITY, l = 0.f;
    float acc[8] = {0,0,0,0,0,0,0,0};
    const float* tvp = &topV[qg*32];
    const int*   tip = &topI[qg*32];
    #pragma unroll 8
    for (int j=0;j<32;j++) m = fmaxf(m, tvp[j]*SCALE);
    #pragma unroll 4
    for (int j=0;j<32;j++) {
        float p = __expf(tvp[j]*SCALE - m);
        l += p;
        const float* mvr = &memv[((size_t)bh*M_ + tip[j])*HD + dd0];
        float4 a  = *(const float4*)&mvr[0];
        float4 b2 = *(const float4*)&mvr[4];
        acc[0]+=p*a.x;  acc[1]+=p*a.y;  acc[2]+=p*a.z;  acc[3]+=p*a.w;
        acc[4]+=p*b2.x; acc[5]+=p*b2.y; acc[6]+=p*b2.z; acc[7]+=p*b2.w;
    }
    const int ntiles = (qt*32 + 31)/64 + 1;
    const float* kb2 = k + ((size_t)bh*S_)*HD;
    const float* vb2 = v + ((size_t)bh*S_)*HD;
    for (int kt=0; kt<ntiles; kt++) {
        __syncthreads();
        for (int fi=tid; fi<1024; fi+=256) {
            int r = fi>>4, c = (fi&15)<<2;
            *(float4*)&Ks[r][c] = *(const float4*)&kb2[(size_t)(kt*64+r)*HD + c];
            *(float4*)&Vs[r][c] = *(const float4*)&vb2[(size_t)(kt*64+r)*HD + c];
        }
        __syncthreads();
        float s8[8];
        #pragma unroll
        for (int rr=0; rr<8; rr++) {
            int row = lg + (rr<<3);
            float acc2 = 0.f;
            #pragma unroll
            for (int j=0;j<64;j+=4) {
                float4 kv = *(const float4*)&Ks[row][j];
                acc2 += qreg[j]*kv.x + qreg[j+1]*kv.y + qreg[j+2]*kv.z + qreg[j+3]*kv.w;
            }
            int kpos = kt*64 + row;
            s8[rr] = (kpos <= qpos) ? acc2 : -INFINITY;
        }
        float tmax = s8[0];
        #pragma unroll
        for (int rr=1; rr<8; rr++) tmax = fmaxf(tmax, s8[rr]);
        #pragma unroll
        for (int off=1; off<8; off<<=1) tmax = fmaxf(tmax, __shfl_xor(tmax, off));
        float mnew = fmaxf(m, tmax);
        float f = __expf(m - mnew);
        l *= f;
        #pragma unroll
        for (int i=0;i<8;i++) acc[i] *= f;
        float psum = 0.f;
        #pragma unroll
        for (int rr=0; rr<8; rr++) {
            float p = __expf(s8[rr] - mnew);
            psum += p;
            pt[ql][lg + (rr<<3)] = p;
        }
        #pragma unroll
        for (int off=1; off<8; off<<=1) psum += __shfl_xor(psum, off);
        l += psum; m = mnew;
        #pragma unroll 8
        for (int r=0; r<64; r++) {
            float p = pt[ql][r];
            float4 a  = *(const float4*)&Vs[r][dd0];
            float4 b2 = *(const float4*)&Vs[r][dd0+4];
            acc[0]+=p*a.x;  acc[1]+=p*a.y;  acc[2]+=p*a.z;  acc[3]+=p*a.w;
            acc[4]+=p*b2.x; acc[5]+=p*b2.y; acc[6]+=p*b2.z; acc[7]+=p*b2.w;
        }
    }
    float inv = 1.0f / l;
    const int b = bh>>4, h = bh&15;
    float4 o;
    o.x=acc[0]*inv; o.y=acc[1]*inv; o.z=acc[2]*inv; o.w=acc[3]*inv;
    *(float4*)&attn[((size_t)(b*S_)+qpos)*HDIM + h*HD + dd0] = o;
    o.x=acc[4]*inv; o.y=acc[5]*inv; o.z=acc[6]*inv; o.w=acc[7]*inv;
    *(float4*)&attn[((size_t)(b*S_)+qpos)*HDIM + h*HD + dd0 + 4] = o;
}

extern "C" void kernel_launch(void* const* d_in, const int* in_sizes, int n_in,
                              void* d_out, int out_size, void* d_ws, size_t ws_size,
                              hipStream_t stream)
{
    const float* hs   = (const float*)d_in[0];
    const float* cosb = (const float*)d_in[1];
    const float* sinb = (const float*)d_in[2];
    const float* memk = (const float*)d_in[3];
    const float* memv = (const float*)d_in[4];
    const float* Wq = (const float*)d_in[5];
    const float* bq = (const float*)d_in[6];
    const float* Wk = (const float*)d_in[7];
    const float* bk = (const float*)d_in[8];
    const float* Wv = (const float*)d_in[9];
    const float* bv = (const float*)d_in[10];
    const float* Wo = (const float*)d_in[11];
    float* out = (float*)d_out;
    float* ws = (float*)d_ws;
    float* qw = ws;                    // 1M floats
    float* kw = ws + 1048576;          // 1M
    float* vw = ws + 2097152;          // 1M
    float* tV = ws + 3145728;          // 512K
    int*   tI = (int*)(ws + 3670016);  // 512K
    unsigned short* kb16 = (unsigned short*)(ws + 4194304); // 8.39M float-slots
    float* ao = ws + 4194304;          // aliases kb16 (dead before attn writes)

    qkv_tobf16<<<8960,256,0,stream>>>(memk, kb16, hs, Wq,bq,Wk,bk,Wv,bv, qw,kw,vw);
    rope_kernel<<<4096,256,0,stream>>>(qw,kw,cosb,sinb);
    sim_topk_mfma<<<256,1024,0,stream>>>(qw, memk, kb16, tV, tI);
    attn_fused<<<dim3(16,32),256,0,stream>>>(qw,kw,vw, tV,tI, memv, ao);
    out_gemm<<<dim3(16,16),256,0,stream>>>(ao, Wo, out);
}

// Round 28
// 432.608 us; speedup vs baseline: 1.1280x; 1.1280x over previous
//
#include <hip/hip_runtime.h>
#include <cmath>

#define B_ 2
#define S_ 512
#define D_ 1024
#define H_ 16
#define HD 64
#define M_ 8192
#define HDIM 1024
#define SCALE 0.125f
#define LCAP 12    // per-lane private candidates; 16 lanes/query -> top-192 screen
#define NRES 3     // rescored candidates per lane (top-48 of 192 by key)

using bf16x8 = __attribute__((ext_vector_type(8))) short;
using f32x4  = __attribute__((ext_vector_type(4))) float;

// pack two f32 (hi,lo) -> one u32 holding [bf16(lo) | bf16(hi)<<16] (truncation)
__device__ inline unsigned pkbf(unsigned hi, unsigned lo) {
    return __builtin_amdgcn_perm(hi, lo, 0x07060302u);
}
// monotone u16 sort keys for 2 packed bf16 (order-preserving for floats)
__device__ inline unsigned key2(unsigned u) {
    unsigned m = u & 0x80008000u;
    return u ^ (m - (m >> 15)) ^ 0x80008000u;
}

// DPP lane moves (full-rate VALU). 0x140=row_mirror (i^15 within 16),
// 0x141=row_half_mirror (i^7), 0x4E=quad_perm xor2, 0xB1=quad_perm xor1.
template<int CTRL>
__device__ inline int dppmov(int x) {
    return __builtin_amdgcn_update_dpp(0, x, CTRL, 0xF, 0xF, true);
}

// ---------------- K0: memk f32 -> bf16 prepass (truncation) ----------------
__global__ __launch_bounds__(256) void tobf16(
    const float* __restrict__ in, unsigned short* __restrict__ out)
{
    size_t i = ((size_t)blockIdx.x*256 + threadIdx.x) * 8;
    f32x4 a = *(const f32x4*)&in[i];
    f32x4 b = *(const f32x4*)&in[i+4];
    union { bf16x8 v; unsigned u[4]; } u;
    u.u[0] = pkbf(__float_as_uint(a.y), __float_as_uint(a.x));
    u.u[1] = pkbf(__float_as_uint(a.w), __float_as_uint(a.z));
    u.u[2] = pkbf(__float_as_uint(b.y), __float_as_uint(b.x));
    u.u[3] = pkbf(__float_as_uint(b.w), __float_as_uint(b.z));
    *(bf16x8*)&out[i] = u.v;
}

// ---------------- K1: QKV projection GEMM (64x64 tile, f32) ----------------
__global__ __launch_bounds__(256) void qkv_gemm(
    const float* __restrict__ A,
    const float* __restrict__ Wq, const float* __restrict__ bq,
    const float* __restrict__ Wk, const float* __restrict__ bk,
    const float* __restrict__ Wv, const float* __restrict__ bv,
    float* __restrict__ qo, float* __restrict__ ko, float* __restrict__ vo)
{
    const int which = blockIdx.z;
    const float* W    = (which==0)?Wq:((which==1)?Wk:Wv);
    const float* bias = (which==0)?bq:((which==1)?bk:bv);
    float* out        = (which==0)?qo:((which==1)?ko:vo);
    const int rb = blockIdx.y*64, cb = blockIdx.x*64;
    __shared__ float As[16][68];
    __shared__ float Bs[16][68];
    const int tid = threadIdx.x;
    const int ty = tid>>4, tx = tid&15;
    const int ar = tid>>2, ac4 = (tid&3)<<2;
    const int bkr = tid>>4, bc4 = (tid&15)<<2;
    float acc[4][4] = {};
    for (int kb=0; kb<D_; kb+=16) {
        float4 av  = *(const float4*)&A[(size_t)(rb+ar)*D_ + kb + ac4];
        float4 bvv = *(const float4*)&W[(size_t)(kb+bkr)*HDIM + cb + bc4];
        __syncthreads();
        As[ac4+0][ar]=av.x; As[ac4+1][ar]=av.y; As[ac4+2][ar]=av.z; As[ac4+3][ar]=av.w;
        *(float4*)&Bs[bkr][bc4] = bvv;
        __syncthreads();
        #pragma unroll
        for (int kk=0; kk<16; kk++) {
            float a[4], b[4];
            *(float4*)a = *(const float4*)&As[kk][ty<<2];
            *(float4*)b = *(const float4*)&Bs[kk][tx<<2];
            #pragma unroll
            for (int i=0;i<4;i++)
                #pragma unroll
                for (int j=0;j<4;j++) acc[i][j] += a[i]*b[j];
        }
    }
    const int c0 = cb + (tx<<2);
    float4 bb = *(const float4*)&bias[c0];
    const int h = c0>>6, dd = c0&63;
    #pragma unroll
    for (int i=0;i<4;i++) {
        int n = rb + (ty<<2) + i;
        int b = n>>9, s = n&511;
        float4 r;
        r.x = acc[i][0]+bb.x; r.y = acc[i][1]+bb.y;
        r.z = acc[i][2]+bb.z; r.w = acc[i][3]+bb.w;
        *(float4*)&out[((size_t)(b*H_+h)*S_ + s)*HD + dd] = r;
    }
}

// ---------------- K6: output projection GEMM ----------------
__global__ __launch_bounds__(256) void out_gemm(
    const float* __restrict__ A, const float* __restrict__ W, float* __restrict__ out)
{
    const int rb = blockIdx.y*64, cb = blockIdx.x*64;
    __shared__ float As[16][68];
    __shared__ float Bs[16][68];
    const int tid = threadIdx.x;
    const int ty = tid>>4, tx = tid&15;
    const int ar = tid>>2, ac4 = (tid&3)<<2;
    const int bkr = tid>>4, bc4 = (tid&15)<<2;
    float acc[4][4] = {};
    for (int kb=0; kb<HDIM; kb+=16) {
        float4 av  = *(const float4*)&A[(size_t)(rb+ar)*HDIM + kb + ac4];
        float4 bvv = *(const float4*)&W[(size_t)(kb+bkr)*D_ + cb + bc4];
        __syncthreads();
        As[ac4+0][ar]=av.x; As[ac4+1][ar]=av.y; As[ac4+2][ar]=av.z; As[ac4+3][ar]=av.w;
        *(float4*)&Bs[bkr][bc4] = bvv;
        __syncthreads();
        #pragma unroll
        for (int kk=0; kk<16; kk++) {
            float a[4], b[4];
            *(float4*)a = *(const float4*)&As[kk][ty<<2];
            *(float4*)b = *(const float4*)&Bs[kk][tx<<2];
            #pragma unroll
            for (int i=0;i<4;i++)
                #pragma unroll
                for (int j=0;j<4;j++) acc[i][j] += a[i]*b[j];
        }
    }
    const int c0 = cb + (tx<<2);
    #pragma unroll
    for (int i=0;i<4;i++) {
        int n = rb + (ty<<2) + i;
        float4 r;
        r.x=acc[i][0]; r.y=acc[i][1]; r.z=acc[i][2]; r.w=acc[i][3];
        *(float4*)&out[(size_t)n*D_ + c0] = r;
    }
}

// ---------------- K2: RoPE in-place on q,k ----------------
__global__ __launch_bounds__(256) void rope_kernel(
    float* __restrict__ q, float* __restrict__ k,
    const float* __restrict__ cosb, const float* __restrict__ sinb)
{
    int t = blockIdx.x*256 + threadIdx.x;
    int pair = t & 31;
    int s    = (t>>5) & 511;
    int bh   = (t>>14) & 31;
    float* x = (t>>19) ? k : q;
    float* xb = x + ((size_t)(bh*S_ + s))*HD;
    float c  = cosb[s*HD + pair];
    float sn = sinb[s*HD + pair];
    float x1 = xb[pair], x2 = xb[pair+32];
    xb[pair]    = x1*c - x2*sn;
    xb[pair+32] = x2*c + x1*sn;
}

// ---------------- K3: MFMA sim + screen (dbuf, wave-skip ladder) -----------
// 256 blocks x 1024 thr (16 waves). Block: 64 queries x full M, tile=128,
// bf16 stream, double-buffered Ks+sc, ONE barrier/tile. Ladder guarded by
// __any(key > lane-min): skipping is exact (below-min inserts are no-ops on
// a sorted-desc list). Screen/rescore semantics identical to R21/R22.
__global__ __launch_bounds__(1024, 4) void sim_topk_mfma(
    const float* __restrict__ q, const float* __restrict__ memk,
    const unsigned short* __restrict__ kb16,
    float* __restrict__ topV, int* __restrict__ topI)
{
    __shared__ unsigned short sc[2][64][136];
    __shared__ __align__(16) float qs[64][64];
    __shared__ __align__(16) unsigned short Ks[2][128][76];
    const int tid = threadIdx.x;
    int id = blockIdx.x;                 // 0..255
    int virt = (id & 7)*32 + (id >> 3);
    const int bh = virt >> 3, qt = virt & 7;
    const float* qbase = q + ((size_t)bh*S_ + qt*64)*HD;
    const float* kbase = memk + (size_t)bh*M_*HD;
    const unsigned short* k16 = kb16 + (size_t)bh*M_*HD;

    {   // stage q f32 (64x64): one f32x4 per thread
        int r = tid >> 4, c = (tid & 15) << 2;
        *(f32x4*)&qs[r][c] = *(const f32x4*)&qbase[(size_t)r*HD + c];
    }
    __syncthreads();

    const int lane = tid & 63;
    const int w  = tid >> 6;                  // wave 0..15
    const int s8 = w & 7;                     // m-subtile (rows s8*16..+15)
    const int qg = w >> 3;                    // qh-group: qh = 2*qg, 2*qg+1
    const int fr = lane & 15, fc = lane >> 4; // frag row / k-chunk

    bf16x8 bq[2][2];
    #pragma unroll
    for (int j = 0; j < 2; j++)
        #pragma unroll
        for (int kc = 0; kc < 2; kc++) {
            const float* p = &qs[(2*qg + j)*16 + fr][kc*32 + 8*fc];
            union { bf16x8 v; unsigned u[4]; } u;
            #pragma unroll
            for (int jj = 0; jj < 4; jj++)
                u.u[jj] = pkbf(__float_as_uint(p[2*jj+1]), __float_as_uint(p[2*jj]));
            bq[j][kc] = u.v;
        }

    const int ql = tid >> 4, lg = tid & 15;   // query row / lane-in-group
    unsigned xs[LCAP];
    #pragma unroll
    for (int s = 0; s < LCAP; s++) xs[s] = 0u;

    const int srow = tid >> 3, scol = (tid & 7) << 3;

    uint4 pfu;
    {
        uint4 t0 = *(const uint4*)&k16[(size_t)srow*HD + scol];
        *(uint4*)&Ks[0][srow][scol] = t0;
        pfu = *(const uint4*)&k16[(size_t)(128 + srow)*HD + scol];
    }
    __syncthreads();   // Ks[0] ready

    for (int it = 0; it < 64; it++) {
        const int cur = it & 1, nxt = cur ^ 1;
        if (it < 63) {
            *(uint4*)&Ks[nxt][srow][scol] = pfu;
        }
        if (it < 62) {
            pfu = *(const uint4*)&k16[(size_t)((it+2)*128 + srow)*HD + scol];
        }
        {
            bf16x8 a0 = *(const bf16x8*)&Ks[cur][s8*16 + fr][8*fc];
            bf16x8 a1 = *(const bf16x8*)&Ks[cur][s8*16 + fr][32 + 8*fc];
            #pragma unroll
            for (int j = 0; j < 2; j++) {
                f32x4 acc = (f32x4){0.f, 0.f, 0.f, 0.f};
                acc = __builtin_amdgcn_mfma_f32_16x16x32_bf16(a0, bq[j][0], acc, 0,0,0);
                acc = __builtin_amdgcn_mfma_f32_16x16x32_bf16(a1, bq[j][1], acc, 0,0,0);
                unsigned k0 = key2(pkbf(__float_as_uint(acc.y), __float_as_uint(acc.x)));
                unsigned k1 = key2(pkbf(__float_as_uint(acc.w), __float_as_uint(acc.z)));
                uint2 kk; kk.x = k0; kk.y = k1;
                *(uint2*)&sc[cur][(2*qg + j)*16 + fr][s8*16 + 4*fc] = kk;
            }
        }
        if (it > 0) {
            uint4 w0v = *(const uint4*)&sc[cur^1][ql][lg << 3];
            unsigned wbuf[4] = {w0v.x, w0v.y, w0v.z, w0v.w};
            const unsigned ibase = (unsigned)((it-1)*128 + (lg << 3));
            #pragma unroll
            for (int p = 0; p < 4; p++) {
                unsigned wk = wbuf[p];
                unsigned ve = (wk << 16) | (ibase + 2*p);
                unsigned vo = (wk & 0xFFFF0000u) | (ibase + 2*p + 1);
                if (__any(ve > xs[LCAP-1] || vo > xs[LCAP-1])) {
                    #pragma unroll
                    for (int s = 0; s < LCAP; s++) {
                        unsigned mx = xs[s] > ve ? xs[s] : ve;
                        unsigned mn = xs[s] > ve ? ve : xs[s];
                        xs[s] = mx; ve = mn;
                    }
                    #pragma unroll
                    for (int s = 0; s < LCAP; s++) {
                        unsigned mx = xs[s] > vo ? xs[s] : vo;
                        unsigned mn = xs[s] > vo ? vo : xs[s];
                        xs[s] = mx; vo = mn;
                    }
                }
            }
        }
        __syncthreads();
    }
    {
        uint4 w0v = *(const uint4*)&sc[1][ql][lg << 3];
        unsigned wbuf[4] = {w0v.x, w0v.y, w0v.z, w0v.w};
        const unsigned ibase = (unsigned)(63*128 + (lg << 3));
        #pragma unroll
        for (int p = 0; p < 4; p++) {
            unsigned wk = wbuf[p];
            unsigned ve = (wk << 16) | (ibase + 2*p);
            unsigned vo = (wk & 0xFFFF0000u) | (ibase + 2*p + 1);
            if (__any(ve > xs[LCAP-1] || vo > xs[LCAP-1])) {
                #pragma unroll
                for (int s = 0; s < LCAP; s++) {
                    unsigned mx = xs[s] > ve ? xs[s] : ve;
                    unsigned mn = xs[s] > ve ? ve : xs[s];
                    xs[s] = mx; ve = mn;
                }
                #pragma unroll
                for (int s = 0; s < LCAP; s++) {
                    unsigned mx = xs[s] > vo ? xs[s] : vo;
                    unsigned mn = xs[s] > vo ? vo : xs[s];
                    xs[s] = mx; vo = mn;
                }
            }
        }
    }

    // ---- register extract: group top-48 by key -> 3 collector slots/lane --
    unsigned rc[NRES];
    #pragma unroll
    for (int it = 0; it < 48; it++) {
        unsigned gm = xs[0]; int go = lg;
        { unsigned ov=(unsigned)dppmov<0x140>((int)gm); int oo=dppmov<0x140>(go);
          if (ov > gm) { gm = ov; go = oo; } }
        { unsigned ov=(unsigned)dppmov<0x141>((int)gm); int oo=dppmov<0x141>(go);
          if (ov > gm) { gm = ov; go = oo; } }
        { unsigned ov=(unsigned)dppmov<0x4E>((int)gm);  int oo=dppmov<0x4E>(go);
          if (ov > gm) { gm = ov; go = oo; } }
        { unsigned ov=(unsigned)dppmov<0xB1>((int)gm);  int oo=dppmov<0xB1>(go);
          if (ov > gm) { gm = ov; go = oo; } }
        if (go == lg) {
            #pragma unroll
            for (int s = 0; s < LCAP-1; s++) xs[s] = xs[s+1];
            xs[LCAP-1] = 0u;
        }
        if ((it & 15) == lg) rc[it >> 4] = gm;
    }

    // ---- exact f32 rescore of my NRES candidates ----
    float rsv[NRES]; int rsi[NRES];
    #pragma unroll
    for (int s2 = 0; s2 < NRES; s2++) {
        int idx = (int)(rc[s2] & 0xFFFFu);
        const float* kr = &kbase[(size_t)idx * HD];
        float accr = 0.f;
        #pragma unroll
        for (int j = 0; j < 64; j += 4) {
            f32x4 kv = *(const f32x4*)&kr[j];
            f32x4 qv = *(const f32x4*)&qs[ql][j];
            accr += qv.x*kv.x + qv.y*kv.y + qv.z*kv.z + qv.w*kv.w;
        }
        rsv[s2] = accr; rsi[s2] = idx;
    }
    // ---- exact top-32 of 48 by extract-max (16-lane DPP argmax) ----
    const int qgb = bh*S_ + qt*64;
    float* tVo = &topV[(size_t)(qgb + ql)*32];
    int*   tIo = &topI[(size_t)(qgb + ql)*32];
    #pragma unroll 1
    for (int it = 0; it < 32; it++) {
        float mv = rsv[0]; int ms = 0;
        if (rsv[1] > mv) { mv = rsv[1]; ms = 1; }
        if (rsv[2] > mv) { mv = rsv[2]; ms = 2; }
        int owner = (lg << 2) | ms;
        { float ovf=__int_as_float(dppmov<0x140>(__float_as_int(mv))); int oo=dppmov<0x140>(owner);
          if (ovf>mv || (ovf==mv && oo<owner)) { mv=ovf; owner=oo; } }
        { float ovf=__int_as_float(dppmov<0x141>(__float_as_int(mv))); int oo=dppmov<0x141>(owner);
          if (ovf>mv || (ovf==mv && oo<owner)) { mv=ovf; owner=oo; } }
        { float ovf=__int_as_float(dppmov<0x4E>(__float_as_int(mv)));  int oo=dppmov<0x4E>(owner);
          if (ovf>mv || (ovf==mv && oo<owner)) { mv=ovf; owner=oo; } }
        { float ovf=__int_as_float(dppmov<0xB1>(__float_as_int(mv)));  int oo=dppmov<0xB1>(owner);
          if (ovf>mv || (ovf==mv && oo<owner)) { mv=ovf; owner=oo; } }
        if ((owner >> 2) == lg) {
            int ms2 = owner & 3;
            int idx = rsi[0];
            if (ms2 == 1) idx = rsi[1];
            else if (ms2 == 2) idx = rsi[2];
            if (ms2 == 0) rsv[0] = -INFINITY;
            else if (ms2 == 1) rsv[1] = -INFINITY;
            else rsv[2] = -INFINITY;
            tVo[it] = mv; tIo[it] = idx;
        }
    }
}

// ---------------- K5: fused local-causal + memory attention ----------------
__global__ __launch_bounds__(256) void attn_fused(
    const float* __restrict__ q, const float* __restrict__ k, const float* __restrict__ v,
    const float* __restrict__ topV, const int* __restrict__ topI,
    const float* __restrict__ memv, float* __restrict__ attn)
{
    __shared__ float Ks[64][68];
    __shared__ float Vs[64][68];
    __shared__ float Qs[32][68];
    __shared__ float pt[32][68];
    const int tid = threadIdx.x;
    const int qt = blockIdx.x, bh = blockIdx.y;
    const float* qbase = q + ((size_t)bh*S_ + qt*32)*HD;
    {
        int fi = tid; int r = fi>>4, c = (fi&15)<<2;
        float4 t4 = *(const float4*)&qbase[(size_t)r*HD + c];
        t4.x*=SCALE; t4.y*=SCALE; t4.z*=SCALE; t4.w*=SCALE;
        *(float4*)&Qs[r][c] = t4;
        fi = tid+256; r = fi>>4; c = (fi&15)<<2;
        t4 = *(const float4*)&qbase[(size_t)r*HD + c];
        t4.x*=SCALE; t4.y*=SCALE; t4.z*=SCALE; t4.w*=SCALE;
        *(float4*)&Qs[r][c] = t4;
    }
    __syncthreads();
    const int ql = tid>>3, lg = tid&7;
    const int dd0 = lg<<3;
    float qreg[64];
    #pragma unroll
    for (int j=0;j<64;j+=4) *(float4*)&qreg[j] = *(const float4*)&Qs[ql][j];
    const int qpos = qt*32 + ql;
    const size_t qg = (size_t)bh*S_ + qpos;

    float m = -INFINITY, l = 0.f;
    float acc[8] = {0,0,0,0,0,0,0,0};
    const float* tvp = &topV[qg*32];
    const int*   tip = &topI[qg*32];
    #pragma unroll 8
    for (int j=0;j<32;j++) m = fmaxf(m, tvp[j]*SCALE);
    #pragma unroll 4
    for (int j=0;j<32;j++) {
        float p = __expf(tvp[j]*SCALE - m);
        l += p;
        const float* mvr = &memv[((size_t)bh*M_ + tip[j])*HD + dd0];
        float4 a  = *(const float4*)&mvr[0];
        float4 b2 = *(const float4*)&mvr[4];
        acc[0]+=p*a.x;  acc[1]+=p*a.y;  acc[2]+=p*a.z;  acc[3]+=p*a.w;
        acc[4]+=p*b2.x; acc[5]+=p*b2.y; acc[6]+=p*b2.z; acc[7]+=p*b2.w;
    }
    const int ntiles = (qt*32 + 31)/64 + 1;
    const float* kb2 = k + ((size_t)bh*S_)*HD;
    const float* vb2 = v + ((size_t)bh*S_)*HD;
    for (int kt=0; kt<ntiles; kt++) {
        __syncthreads();
        for (int fi=tid; fi<1024; fi+=256) {
            int r = fi>>4, c = (fi&15)<<2;
            *(float4*)&Ks[r][c] = *(const float4*)&kb2[(size_t)(kt*64+r)*HD + c];
            *(float4*)&Vs[r][c] = *(const float4*)&vb2[(size_t)(kt*64+r)*HD + c];
        }
        __syncthreads();
        float s8[8];
        #pragma unroll
        for (int rr=0; rr<8; rr++) {
            int row = lg + (rr<<3);
            float acc2 = 0.f;
            #pragma unroll
            for (int j=0;j<64;j+=4) {
                float4 kv = *(const float4*)&Ks[row][j];
                acc2 += qreg[j]*kv.x + qreg[j+1]*kv.y + qreg[j+2]*kv.z + qreg[j+3]*kv.w;
            }
            int kpos = kt*64 + row;
            s8[rr] = (kpos <= qpos) ? acc2 : -INFINITY;
        }
        float tmax = s8[0];
        #pragma unroll
        for (int rr=1; rr<8; rr++) tmax = fmaxf(tmax, s8[rr]);
        #pragma unroll
        for (int off=1; off<8; off<<=1) tmax = fmaxf(tmax, __shfl_xor(tmax, off));
        float mnew = fmaxf(m, tmax);
        float f = __expf(m - mnew);
        l *= f;
        #pragma unroll
        for (int i=0;i<8;i++) acc[i] *= f;
        float psum = 0.f;
        #pragma unroll
        for (int rr=0; rr<8; rr++) {
            float p = __expf(s8[rr] - mnew);
            psum += p;
            pt[ql][lg + (rr<<3)] = p;
        }
        #pragma unroll
        for (int off=1; off<8; off<<=1) psum += __shfl_xor(psum, off);
        l += psum; m = mnew;
        #pragma unroll 8
        for (int r=0; r<64; r++) {
            float p = pt[ql][r];
            float4 a  = *(const float4*)&Vs[r][dd0];
            float4 b2 = *(const float4*)&Vs[r][dd0+4];
            acc[0]+=p*a.x;  acc[1]+=p*a.y;  acc[2]+=p*a.z;  acc[3]+=p*a.w;
            acc[4]+=p*b2.x; acc[5]+=p*b2.y; acc[6]+=p*b2.z; acc[7]+=p*b2.w;
        }
    }
    float inv = 1.0f / l;
    const int b = bh>>4, h = bh&15;
    float4 o;
    o.x=acc[0]*inv; o.y=acc[1]*inv; o.z=acc[2]*inv; o.w=acc[3]*inv;
    *(float4*)&attn[((size_t)(b*S_)+qpos)*HDIM + h*HD + dd0] = o;
    o.x=acc[4]*inv; o.y=acc[5]*inv; o.z=acc[6]*inv; o.w=acc[7]*inv;
    *(float4*)&attn[((size_t)(b*S_)+qpos)*HDIM + h*HD + dd0 + 4] = o;
}

extern "C" void kernel_launch(void* const* d_in, const int* in_sizes, int n_in,
                              void* d_out, int out_size, void* d_ws, size_t ws_size,
                              hipStream_t stream)
{
    const float* hs   = (const float*)d_in[0];
    const float* cosb = (const float*)d_in[1];
    const float* sinb = (const float*)d_in[2];
    const float* memk = (const float*)d_in[3];
    const float* memv = (const float*)d_in[4];
    const float* Wq = (const float*)d_in[5];
    const float* bq = (const float*)d_in[6];
    const float* Wk = (const float*)d_in[7];
    const float* bk = (const float*)d_in[8];
    const float* Wv = (const float*)d_in[9];
    const float* bv = (const float*)d_in[10];
    const float* Wo = (const float*)d_in[11];
    float* out = (float*)d_out;
    float* ws = (float*)d_ws;
    float* qw = ws;                    // 1M floats
    float* kw = ws + 1048576;          // 1M
    float* vw = ws + 2097152;          // 1M
    float* tV = ws + 3145728;          // 512K
    int*   tI = (int*)(ws + 3670016);  // 512K
    unsigned short* kb16 = (unsigned short*)(ws + 4194304); // 8.39M float-slots
    float* ao = ws + 4194304;          // aliases kb16 (dead before attn writes)

    tobf16<<<8192,256,0,stream>>>(memk, kb16);
    qkv_gemm<<<dim3(16,16,3),256,0,stream>>>(hs, Wq,bq,Wk,bk,Wv,bv, qw,kw,vw);
    rope_kernel<<<4096,256,0,stream>>>(qw,kw,cosb,sinb);
    sim_topk_mfma<<<256,1024,0,stream>>>(qw, memk, kb16, tV, tI);
    attn_fused<<<dim3(16,32),256,0,stream>>>(qw,kw,vw, tV,tI, memv, ao);
    out_gemm<<<dim3(16,16),256,0,stream>>>(ao, Wo, out);
}